// Round 12
// baseline (113.875 us; speedup 1.0000x reference)
//
#include <hip/hip_runtime.h>
#include <hip/hip_bf16.h>
#include <stdint.h>

typedef __attribute__((ext_vector_type(8)))  __bf16   bf16x8;
typedef __attribute__((ext_vector_type(4)))  float    f32x4;
typedef __attribute__((ext_vector_type(16))) float    f32x16;
typedef __attribute__((ext_vector_type(4)))  unsigned u32x4;
typedef __attribute__((ext_vector_type(2)))  unsigned u32x2;

#define BATCH  2
#define SEQ    2048
#define DMODEL 1024
#define NHEAD  16
#define HDIM   64
#define MTOT   (BATCH * SEQ)   // 4096
#define MOFF   8.0f            // fixed softmax offset (exp2 domain)

// async global->LDS, 16B per lane (dest = wave-uniform base + lane*16)
__device__ __forceinline__ void gload_lds16(const void* g, void* l) {
  __builtin_amdgcn_global_load_lds(
      (const __attribute__((address_space(1))) unsigned int*)g,
      (__attribute__((address_space(3))) unsigned int*)(uintptr_t)l,
      16, 0, 0);
}

// pack two f32 -> one dword of 2 bf16 (compiler emits v_cvt_pk_bf16_f32)
__device__ __forceinline__ unsigned pkbf(float a, float b) {
  unsigned lo = (unsigned)__builtin_bit_cast(unsigned short, (__bf16)a);
  unsigned hb = (unsigned)__builtin_bit_cast(unsigned short, (__bf16)b);
  return lo | (hb << 16);
}

// ---------- fused fp32 -> bf16 casts (all 5 tensors, one launch) ----------
__global__ void cast_all(const float* __restrict__ x,  const float* __restrict__ wq,
                         const float* __restrict__ wk, const float* __restrict__ wv,
                         const float* __restrict__ wo,
                         __bf16* __restrict__ xb,  __bf16* __restrict__ wqb,
                         __bf16* __restrict__ wkb, __bf16* __restrict__ wvb,
                         __bf16* __restrict__ wob)
{
  const float* in; __bf16* out; int n;
  switch (blockIdx.y) {
    case 0:  in = x;  out = xb;  n = MTOT * DMODEL;   break;
    case 1:  in = wq; out = wqb; n = DMODEL * DMODEL; break;
    case 2:  in = wk; out = wkb; n = DMODEL * DMODEL; break;
    case 3:  in = wv; out = wvb; n = DMODEL * DMODEL; break;
    default: in = wo; out = wob; n = DMODEL * DMODEL; break;
  }
  const int i = blockIdx.x * blockDim.x + threadIdx.x;
  const int stride = gridDim.x * blockDim.x;
  for (int idx = i; idx * 8 < n; idx += stride) {
    const float4 a = ((const float4*)in)[idx * 2];
    const float4 b = ((const float4*)in)[idx * 2 + 1];
    bf16x8 v = { (__bf16)a.x, (__bf16)a.y, (__bf16)a.z, (__bf16)a.w,
                 (__bf16)b.x, (__bf16)b.y, (__bf16)b.z, (__bf16)b.w };
    *(bf16x8*)(out + (size_t)idx * 8) = v;
  }
}

// ---------- qkv 128x128 mainloop, BK=64 (halved barrier count) ----------
// 4 waves; per 64-wide k-step: stage 128x64 A and B (32KB LDS), then two
// kc-substeps reuse the same fragment registers -> VGPR stays ~164,
// 3 blocks/CU (LDS 96KB, VGPR) preserved; barriers 64 -> 32 per block.
__device__ __forceinline__ void gemm_tile_128_bk64(const __bf16* __restrict__ A,
                                                   const __bf16* __restrict__ W,
                                                   int bm, int bn, int Kd,
                                                   f32x4 (&acc)[4][4])
{
  __shared__ __align__(16) __bf16 As[128 * 64];
  __shared__ __align__(16) __bf16 Bs[128 * 64];
  const int tid  = threadIdx.x;
  const int wave = tid >> 6, lane = tid & 63;
  const int wr = wave >> 1, wc = wave & 1;
  const int fr = lane & 15, fq = lane >> 4;

  // chunk c (0..1023): row = c>>3, col8 = (c&7)*8 within the 128x64 tile
  const __bf16* gA[4];
  const __bf16* gB[4];
#pragma unroll
  for (int i = 0; i < 4; ++i) {
    const int c = tid + 256 * i;
    gA[i] = A + (size_t)(bm * 128 + (c >> 3)) * Kd + (c & 7) * 8;
    gB[i] = W + (size_t)(bn * 128 + (c >> 3)) * Kd + (c & 7) * 8;
  }

  for (int k0 = 0; k0 < Kd; k0 += 64) {
#pragma unroll
    for (int i = 0; i < 4; ++i) {
      gload_lds16(gA[i] + k0, As + (tid + 256 * i) * 8);
      gload_lds16(gB[i] + k0, Bs + (tid + 256 * i) * 8);
    }
    __syncthreads();
#pragma unroll
    for (int kc = 0; kc < 2; ++kc) {
      bf16x8 a[4], b[4];
#pragma unroll
      for (int m = 0; m < 4; ++m)
        a[m] = *(const bf16x8*)(As + (wr * 64 + m * 16 + fr) * 64 + kc * 32 + fq * 8);
#pragma unroll
      for (int n = 0; n < 4; ++n)
        b[n] = *(const bf16x8*)(Bs + (wc * 64 + n * 16 + fr) * 64 + kc * 32 + fq * 8);
#pragma unroll
      for (int m = 0; m < 4; ++m)
#pragma unroll
        for (int n = 0; n < 4; ++n)
          acc[m][n] = __builtin_amdgcn_mfma_f32_16x16x32_bf16(a[m], b[n], acc[m][n], 0, 0, 0);
    }
    __syncthreads();
  }
}

// ---------- QKV projections ----------
// z=0: Q (row-major, *qscale). z=1: K packed fragment-order. z=2: V packed
// fragment-order (computed as VT = Wv * x^T).
// PK layout: [b][h][t32=64][kc=4][lane=64][j=8]   (256KB per (b,h))
// PV layout: [b][h][t64=32][db=2][kc=4][lane=64][j=8]
__global__ __launch_bounds__(256)
void gemm_qkv(const __bf16* __restrict__ xb,
              const __bf16* __restrict__ Wq, const __bf16* __restrict__ Wk,
              const __bf16* __restrict__ Wv,
              __bf16* __restrict__ Qo, __bf16* __restrict__ Ko, __bf16* __restrict__ VTo,
              float qscale)
{
  const int z = blockIdx.z;
  const __bf16* A; const __bf16* W; __bf16* Ob; int bm, bn;
  if (z == 2)      { A = Wv; W = xb; Ob = VTo; bm = blockIdx.y; bn = blockIdx.x; }
  else if (z == 1) { A = xb; W = Wk; Ob = Ko;  bm = blockIdx.x; bn = blockIdx.y; }
  else             { A = xb; W = Wq; Ob = Qo;  bm = blockIdx.x; bn = blockIdx.y; }

  f32x4 acc[4][4] = {};
  gemm_tile_128_bk64(A, W, bm, bn, DMODEL, acc);

  const int lane = threadIdx.x & 63, wave = threadIdx.x >> 6;
  const int wr = wave >> 1, wc = wave & 1;
  const int fr = lane & 15, fq = lane >> 4;

  if (z == 0) {
#pragma unroll
    for (int m = 0; m < 4; ++m)
#pragma unroll
      for (int n = 0; n < 4; ++n) {
        const int col = bn * 128 + wc * 64 + n * 16 + fr;
#pragma unroll
        for (int j = 0; j < 4; ++j) {
          const int row = bm * 128 + wr * 64 + m * 16 + fq * 4 + j;
          Ob[(size_t)row * DMODEL + col] = (__bf16)(acc[m][n][j] * qscale);
        }
      }
  } else if (z == 1) {
    // K packed: row = token, col = feature
#pragma unroll
    for (int m = 0; m < 4; ++m)
#pragma unroll
      for (int n = 0; n < 4; ++n) {
        const int f = bn * 128 + wc * 64 + n * 16 + fr;
        const int h = f >> 6;
        const int kc = (f >> 4) & 3, hi = (f >> 3) & 1, jj = f & 7;
#pragma unroll
        for (int j = 0; j < 4; ++j) {
          const int tkn = bm * 128 + wr * 64 + m * 16 + fq * 4 + j;
          const int bb = tkn >> 11, n2 = tkn & 2047;
          const int t32 = n2 >> 5, ln2 = n2 & 31;
          const size_t idx = (((((size_t)bb * 16 + h) * 64 + t32) * 4 + kc) * 64
                              + (ln2 + (hi << 5))) * 8 + jj;
          Ob[idx] = (__bf16)acc[m][n][j];
        }
      }
  } else {
    // V packed: row = feature, col = token
#pragma unroll
    for (int m = 0; m < 4; ++m)
#pragma unroll
      for (int n = 0; n < 4; ++n) {
        const int tkn = bn * 128 + wc * 64 + n * 16 + fr;
        const int bb = tkn >> 11, n2 = tkn & 2047;
        const int t64 = n2 >> 6, w2 = n2 & 63;
        const int kc = w2 >> 4, hi = (w2 >> 3) & 1, jj = w2 & 7;
#pragma unroll
        for (int j = 0; j < 4; ++j) {
          const int f = bm * 128 + wr * 64 + m * 16 + fq * 4 + j;
          const int h = f >> 6, d = f & 63;
          const int db = d >> 5, ln2 = d & 31;
          const size_t idx = ((((((size_t)bb * 16 + h) * 32 + t64) * 2 + db) * 4 + kc) * 64
                              + (ln2 + (hi << 5))) * 8 + jj;
          Ob[idx] = (__bf16)acc[m][n][j];
        }
      }
  }
}

// ---------- output projection: in-block split-K (8 waves, 2 K-halves) ----------
// Waves 0-3: K in [0,512); waves 4-7: [512,1024). Each group keeps the r7
// 2x2 wave grid (64x64 per wave) -> same MFMA:ds_read ratio; per-wave K-loop
// halves and 2 waves/SIMD cover each other's barrier drains (was 1/SIMD).
// Group-1 partials combine through a 64KB LDS buffer; 96KB total, 1 block/CU.
__global__ __launch_bounds__(512)
void gemm_out(const __bf16* __restrict__ A, const __bf16* __restrict__ W,
              float* __restrict__ OF, const float* __restrict__ bias)
{
  __shared__ __align__(16) __bf16 As[2][128 * 32];
  __shared__ __align__(16) __bf16 Bs[2][128 * 32];
  __shared__ __align__(16) float  Cred[4 * 16 * 64 * 4];   // 64KB

  const int tid  = threadIdx.x;          // 0..511
  const int wave = tid >> 6, lane = tid & 63;
  const int g    = wave >> 2;            // K-half
  const int w4   = wave & 3;
  const int wr = w4 >> 1, wc = w4 & 1;
  const int fr = lane & 15, fq = lane >> 4;
  const int bm = blockIdx.x, bn = blockIdx.y;

  const int tid2 = tid & 255;
  const int c0 = tid2, c1 = tid2 + 256;
  const int kgo = g * 512;
  const __bf16* gA0 = A + (size_t)(bm * 128 + (c0 >> 2)) * DMODEL + (c0 & 3) * 8 + kgo;
  const __bf16* gA1 = A + (size_t)(bm * 128 + (c1 >> 2)) * DMODEL + (c1 & 3) * 8 + kgo;
  const __bf16* gB0 = W + (size_t)(bn * 128 + (c0 >> 2)) * DMODEL + (c0 & 3) * 8 + kgo;
  const __bf16* gB1 = W + (size_t)(bn * 128 + (c1 >> 2)) * DMODEL + (c1 & 3) * 8 + kgo;
  __bf16* Asg = As[g];
  __bf16* Bsg = Bs[g];

  f32x4 acc[4][4] = {};

  for (int k0 = 0; k0 < 512; k0 += 32) {
    gload_lds16(gA0 + k0, Asg + c0 * 8);
    gload_lds16(gB0 + k0, Bsg + c0 * 8);
    gload_lds16(gA1 + k0, Asg + c1 * 8);
    gload_lds16(gB1 + k0, Bsg + c1 * 8);
    __syncthreads();
    bf16x8 a[4], b[4];
#pragma unroll
    for (int m = 0; m < 4; ++m)
      a[m] = *(const bf16x8*)(Asg + (wr * 64 + m * 16 + fr) * 32 + fq * 8);
#pragma unroll
    for (int n = 0; n < 4; ++n)
      b[n] = *(const bf16x8*)(Bsg + (wc * 64 + n * 16 + fr) * 32 + fq * 8);
#pragma unroll
    for (int m = 0; m < 4; ++m)
#pragma unroll
      for (int n = 0; n < 4; ++n)
        acc[m][n] = __builtin_amdgcn_mfma_f32_16x16x32_bf16(a[m], b[n], acc[m][n], 0, 0, 0);
    __syncthreads();
  }

  // group 1 exports partials (quadrant w4): coalesced f32x4 per (m,n)
  if (g == 1) {
#pragma unroll
    for (int m = 0; m < 4; ++m)
#pragma unroll
      for (int n = 0; n < 4; ++n)
        *(f32x4*)&Cred[(((w4 * 16) + m * 4 + n) * 64 + lane) * 4] = acc[m][n];
  }
  __syncthreads();

  // group 0 combines + bias + writes out
  if (g == 0) {
#pragma unroll
    for (int m = 0; m < 4; ++m)
#pragma unroll
      for (int n = 0; n < 4; ++n) {
        const f32x4 part = *(const f32x4*)&Cred[(((w4 * 16) + m * 4 + n) * 64 + lane) * 4];
        const int col = bn * 128 + wc * 64 + n * 16 + fr;
        const float bv = bias[col];
#pragma unroll
        for (int j = 0; j < 4; ++j) {
          const int row = bm * 128 + wr * 64 + m * 16 + fq * 4 + j;
          OF[(size_t)row * DMODEL + col] = acc[m][n][j] + part[j] + bv;
        }
      }
  }
}

// ---------- flash attention (r11, verbatim — proven) ----------
// 1 wave = ONE q-tile stream; the WG's 2 waves split kv tiles by parity.
// qt descending (LPT) + bh%8 == blockIdx%8 (XCD L2). Packed K/V loads.
// Fixed-offset softmax (P=exp2(S-8), offset cancels in normalization) ->
// parity partials combine additively via LDS + 1 barrier.
// Swapped QK^T via 32x32x16 MFMA: S^T[kv][q], q = lane&31.
// C/D layout (m74/m101): col=lane&31, row=(r&3)+8*(r>>2)+4*(lane>>5).

__device__ __forceinline__ void mask_tile(f32x16& sv0, f32x16& sv1,
                                          int kv0, int q0, int ln, int hi)
{
  const int qg = q0 + ln;
#pragma unroll
  for (int r = 0; r < 16; ++r) {
    const int kvo = kv0 + (r & 3) + 8 * (r >> 2) + 4 * hi;
    if (kvo > qg)      sv0[r] = -1e30f;
    if (kvo + 32 > qg) sv1[r] = -1e30f;
  }
}

// pack exp'd P (both 32-kv halves) into PV B-fragments (half-exchange via shfl)
__device__ __forceinline__ void pack_pf(const f32x16& sv0, const f32x16& sv1,
                                        bf16x8 (&pf)[4], int hi)
{
#pragma unroll
  for (int half = 0; half < 2; ++half) {
    const int r0 = half * 8;
    {
      unsigned pk01 = pkbf(sv0[r0 + 0], sv0[r0 + 1]);
      unsigned pk23 = pkbf(sv0[r0 + 2], sv0[r0 + 3]);
      unsigned pk45 = pkbf(sv0[r0 + 4], sv0[r0 + 5]);
      unsigned pk67 = pkbf(sv0[r0 + 6], sv0[r0 + 7]);
      unsigned x01 = (unsigned)__shfl_xor((int)pk01, 32, 64);
      unsigned x23 = (unsigned)__shfl_xor((int)pk23, 32, 64);
      unsigned x45 = (unsigned)__shfl_xor((int)pk45, 32, 64);
      unsigned x67 = (unsigned)__shfl_xor((int)pk67, 32, 64);
      u32x4 uw = { hi ? x45 : pk01, hi ? x67 : pk23,
                   hi ? pk45 : x01, hi ? pk67 : x23 };
      pf[half] = __builtin_bit_cast(bf16x8, uw);
    }
    {
      unsigned pk01 = pkbf(sv1[r0 + 0], sv1[r0 + 1]);
      unsigned pk23 = pkbf(sv1[r0 + 2], sv1[r0 + 3]);
      unsigned pk45 = pkbf(sv1[r0 + 4], sv1[r0 + 5]);
      unsigned pk67 = pkbf(sv1[r0 + 6], sv1[r0 + 7]);
      unsigned x01 = (unsigned)__shfl_xor((int)pk01, 32, 64);
      unsigned x23 = (unsigned)__shfl_xor((int)pk23, 32, 64);
      unsigned x45 = (unsigned)__shfl_xor((int)pk45, 32, 64);
      unsigned x67 = (unsigned)__shfl_xor((int)pk67, 32, 64);
      u32x4 uw = { hi ? x45 : pk01, hi ? x67 : pk23,
                   hi ? pk45 : x01, hi ? pk67 : x23 };
      pf[2 + half] = __builtin_bit_cast(bf16x8, uw);
    }
  }
}

__global__ __launch_bounds__(128, 3)
void attn_kernel(const __bf16* __restrict__ Qg, const __bf16* __restrict__ PK,
                 const __bf16* __restrict__ PV, __bf16* __restrict__ Og)
{
  __shared__ __align__(16) float Cs[2][32][68];   // [parity][q][d+pad]
  __shared__ float Ls[2][2][32];                  // [parity][hi][q]

  const int tid  = threadIdx.x;
  const int p    = tid >> 6;          // wave id = kv parity
  const int lane = tid & 63;
  const int ln = lane & 31, hi = lane >> 5;
  const int bI = blockIdx.x;          // 0..2047
  const int bh = bI & 31;             // bh%8 == blockIdx%8 -> XCD L2 locality
  const int qt = 63 - (bI >> 5);      // q-tile, longest-first (LPT)
  const int b = bh >> 4, h = bh & 15;

  const int q0 = qt * 32;
  const int nt = (qt >> 1) + 1;       // kv tiles of 64

  // packed per-(b,h) bases: 131072 elems each
  const __bf16* Kp = PK + (size_t)(b * 16 + h) * (64 * 4 * 64 * 8);
  const __bf16* Vp = PV + (size_t)(b * 16 + h) * (32 * 2 * 4 * 64 * 8);
  const __bf16* Qp = Qg + ((size_t)b * SEQ + q0 + ln) * DMODEL + h * HDIM + hi * 8;

  // Q fragments (B-operand): q=ln, k = kc*16 + hi*8 + j  (Q pre-scaled 0.125*log2e)
  bf16x8 qf[4];
#pragma unroll
  for (int kc = 0; kc < 4; ++kc)
    qf[kc] = *(const bf16x8*)(Qp + kc * 16);

  f32x16 c0 = {}, c1 = {};
  float l = 0.f;

  for (int t = p; t < nt; t += 2) {
    const __bf16* kt = Kp + (size_t)t * 4096;
    const __bf16* vt = Vp + (size_t)t * 4096;

    bf16x8 kA[4], kB[4];
#pragma unroll
    for (int kc = 0; kc < 4; ++kc) {
      kA[kc] = *(const bf16x8*)(kt + (kc * 64 + lane) * 8);
      kB[kc] = *(const bf16x8*)(kt + 2048 + (kc * 64 + lane) * 8);
    }

    f32x16 s0 = {}, s1 = {};
    __builtin_amdgcn_s_setprio(1);
#pragma unroll
    for (int kc = 0; kc < 4; ++kc) {
      s0 = __builtin_amdgcn_mfma_f32_32x32x16_bf16(kA[kc], qf[kc], s0, 0, 0, 0);
      s1 = __builtin_amdgcn_mfma_f32_32x32x16_bf16(kB[kc], qf[kc], s1, 0, 0, 0);
    }
    __builtin_amdgcn_s_setprio(0);

    bf16x8 vt0[4], vt1[4];
#pragma unroll
    for (int kc = 0; kc < 4; ++kc) {
      vt0[kc] = *(const bf16x8*)(vt + (kc * 64 + lane) * 8);
      vt1[kc] = *(const bf16x8*)(vt + 2048 + (kc * 64 + lane) * 8);
    }

    if (t == nt - 1) mask_tile(s0, s1, t * 64, q0, ln, hi);

#pragma unroll
    for (int r = 0; r < 16; ++r) {
      s0[r] = __builtin_amdgcn_exp2f(s0[r] - MOFF);
      s1[r] = __builtin_amdgcn_exp2f(s1[r] - MOFF);
    }
    float s8[8];
#pragma unroll
    for (int r = 0; r < 8; ++r)
      s8[r] = (s0[r] + s0[r + 8]) + (s1[r] + s1[r + 8]);
#pragma unroll
    for (int r = 0; r < 4; ++r) s8[r] += s8[r + 4];
    l += (s8[0] + s8[1]) + (s8[2] + s8[3]);

    bf16x8 pf[4];
    pack_pf(s0, s1, pf, hi);

    __builtin_amdgcn_s_setprio(1);
#pragma unroll
    for (int kc = 0; kc < 4; ++kc)
      c0 = __builtin_amdgcn_mfma_f32_32x32x16_bf16(vt0[kc], pf[kc], c0, 0, 0, 0);
#pragma unroll
    for (int kc = 0; kc < 4; ++kc)
      c1 = __builtin_amdgcn_mfma_f32_32x32x16_bf16(vt1[kc], pf[kc], c1, 0, 0, 0);
    __builtin_amdgcn_s_setprio(0);
  }

  // ---- export both parity partials (offset-softmax partials add exactly) ----
#pragma unroll
  for (int g = 0; g < 4; ++g) {
    f32x4 v0 = { c0[4*g+0], c0[4*g+1], c0[4*g+2], c0[4*g+3] };
    f32x4 v1 = { c1[4*g+0], c1[4*g+1], c1[4*g+2], c1[4*g+3] };
    *(f32x4*)&Cs[p][ln][g * 8 + hi * 4]      = v0;   // d = g*8+hi*4+j
    *(f32x4*)&Cs[p][ln][32 + g * 8 + hi * 4] = v1;   // d = 32+...
  }
  Ls[p][hi][ln] = l;
  __syncthreads();

  // ---- each wave reduces 16 q-rows and writes out ----
  const int qe = p * 16 + (lane >> 2);
  const int de = (lane & 3) * 16;
  const float lt = Ls[0][0][qe] + Ls[0][1][qe] + Ls[1][0][qe] + Ls[1][1][qe];
  const float inv = 1.0f / lt;
  f32x4 a0 = *(const f32x4*)&Cs[0][qe][de]      + *(const f32x4*)&Cs[1][qe][de];
  f32x4 a1 = *(const f32x4*)&Cs[0][qe][de + 4]  + *(const f32x4*)&Cs[1][qe][de + 4];
  f32x4 a2 = *(const f32x4*)&Cs[0][qe][de + 8]  + *(const f32x4*)&Cs[1][qe][de + 8];
  f32x4 a3 = *(const f32x4*)&Cs[0][qe][de + 12] + *(const f32x4*)&Cs[1][qe][de + 12];
  u32x4 w0 = { pkbf(a0[0] * inv, a0[1] * inv), pkbf(a0[2] * inv, a0[3] * inv),
               pkbf(a1[0] * inv, a1[1] * inv), pkbf(a1[2] * inv, a1[3] * inv) };
  u32x4 w1 = { pkbf(a2[0] * inv, a2[1] * inv), pkbf(a2[2] * inv, a2[3] * inv),
               pkbf(a3[0] * inv, a3[1] * inv), pkbf(a3[2] * inv, a3[3] * inv) };
  __bf16* Op = Og + ((size_t)b * SEQ + q0 + qe) * DMODEL + h * HDIM + de;
  *(u32x4*)(Op)     = w0;
  *(u32x4*)(Op + 8) = w1;
}

// ---------- launch ----------
extern "C" void kernel_launch(void* const* d_in, const int* in_sizes, int n_in,
                              void* d_out, int out_size, void* d_ws, size_t ws_size,
                              hipStream_t stream) {
  (void)in_sizes; (void)n_in; (void)out_size; (void)ws_size;
  const float* x  = (const float*)d_in[0];
  const float* Wq = (const float*)d_in[1];
  const float* Wk = (const float*)d_in[2];
  const float* Wv = (const float*)d_in[3];
  const float* Wo = (const float*)d_in[4];
  const float* bo = (const float*)d_in[5];
  float* out = (float*)d_out;

  __bf16* ws  = (__bf16*)d_ws;
  __bf16* xb  = ws;                                   // 4M elems
  __bf16* Wqb = xb  + (size_t)MTOT * DMODEL;
  __bf16* Wkb = Wqb + (size_t)DMODEL * DMODEL;
  __bf16* Wvb = Wkb + (size_t)DMODEL * DMODEL;
  __bf16* Wob = Wvb + (size_t)DMODEL * DMODEL;
  __bf16* Qb  = Wob + (size_t)DMODEL * DMODEL;        // 4M
  __bf16* Kpk = Qb  + (size_t)MTOT * DMODEL;          // 4M, packed fragment order
  __bf16* Vpk = Kpk + (size_t)MTOT * DMODEL;          // 4M, packed fragment order
  __bf16* ctxb = xb;  // reuse: x is dead after QKV projections

  cast_all<<<dim3(256, 5), 256, 0, stream>>>(x, Wq, Wk, Wv, Wo,
                                             xb, Wqb, Wkb, Wvb, Wob);

  // scale = 1/sqrt(64) * log2(e), folded into Q so softmax uses exp2
  const float qscale = 0.125f * 1.4426950408889634f;
  gemm_qkv<<<dim3(32, 8, 3), 256, 0, stream>>>(xb, Wqb, Wkb, Wvb, Qb, Kpk, Vpk, qscale);

  attn_kernel<<<dim3(2048), 128, 0, stream>>>(Qb, Kpk, Vpk, ctxb);

  gemm_out<<<dim3(32, 8), 512, 0, stream>>>(ctxb, Wob, out, bo);
}

// Round 13
// 98.243 us; speedup vs baseline: 1.1591x; 1.1591x over previous
//
#include <hip/hip_runtime.h>
#include <hip/hip_bf16.h>
#include <stdint.h>

typedef __attribute__((ext_vector_type(8)))  __bf16   bf16x8;
typedef __attribute__((ext_vector_type(4)))  float    f32x4;
typedef __attribute__((ext_vector_type(16))) float    f32x16;
typedef __attribute__((ext_vector_type(4)))  unsigned u32x4;
typedef __attribute__((ext_vector_type(2)))  unsigned u32x2;

#define BATCH  2
#define SEQ    2048
#define DMODEL 1024
#define NHEAD  16
#define HDIM   64
#define MTOT   (BATCH * SEQ)   // 4096
#define MOFF   8.0f            // fixed softmax offset (exp2 domain)

// async global->LDS, 16B per lane (dest = wave-uniform base + lane*16)
__device__ __forceinline__ void gload_lds16(const void* g, void* l) {
  __builtin_amdgcn_global_load_lds(
      (const __attribute__((address_space(1))) unsigned int*)g,
      (__attribute__((address_space(3))) unsigned int*)(uintptr_t)l,
      16, 0, 0);
}

// pack two f32 -> one dword of 2 bf16 (compiler emits v_cvt_pk_bf16_f32)
__device__ __forceinline__ unsigned pkbf(float a, float b) {
  unsigned lo = (unsigned)__builtin_bit_cast(unsigned short, (__bf16)a);
  unsigned hb = (unsigned)__builtin_bit_cast(unsigned short, (__bf16)b);
  return lo | (hb << 16);
}

// ---------- fused fp32 -> bf16 casts (all 5 tensors, one launch) ----------
__global__ void cast_all(const float* __restrict__ x,  const float* __restrict__ wq,
                         const float* __restrict__ wk, const float* __restrict__ wv,
                         const float* __restrict__ wo,
                         __bf16* __restrict__ xb,  __bf16* __restrict__ wqb,
                         __bf16* __restrict__ wkb, __bf16* __restrict__ wvb,
                         __bf16* __restrict__ wob)
{
  const float* in; __bf16* out; int n;
  switch (blockIdx.y) {
    case 0:  in = x;  out = xb;  n = MTOT * DMODEL;   break;
    case 1:  in = wq; out = wqb; n = DMODEL * DMODEL; break;
    case 2:  in = wk; out = wkb; n = DMODEL * DMODEL; break;
    case 3:  in = wv; out = wvb; n = DMODEL * DMODEL; break;
    default: in = wo; out = wob; n = DMODEL * DMODEL; break;
  }
  const int i = blockIdx.x * blockDim.x + threadIdx.x;
  const int stride = gridDim.x * blockDim.x;
  for (int idx = i; idx * 8 < n; idx += stride) {
    const float4 a = ((const float4*)in)[idx * 2];
    const float4 b = ((const float4*)in)[idx * 2 + 1];
    bf16x8 v = { (__bf16)a.x, (__bf16)a.y, (__bf16)a.z, (__bf16)a.w,
                 (__bf16)b.x, (__bf16)b.y, (__bf16)b.z, (__bf16)b.w };
    *(bf16x8*)(out + (size_t)idx * 8) = v;
  }
}

// ---------- shared 128x128 GEMM mainloop, BK=32 (r7-proven, 0 conflicts) ----------
__device__ __forceinline__ void gemm_tile_128(const __bf16* __restrict__ A,
                                              const __bf16* __restrict__ W,
                                              int bm, int bn, int Kd,
                                              f32x4 (&acc)[4][4])
{
  __shared__ __align__(16) __bf16 As[128 * 32];
  __shared__ __align__(16) __bf16 Bs[128 * 32];
  const int tid  = threadIdx.x;
  const int wave = tid >> 6, lane = tid & 63;
  const int wr = wave >> 1, wc = wave & 1;
  const int fr = lane & 15, fq = lane >> 4;
  const int c0 = tid, c1 = tid + 256;
  const __bf16* gA0 = A + (size_t)(bm * 128 + (c0 >> 2)) * Kd + (c0 & 3) * 8;
  const __bf16* gA1 = A + (size_t)(bm * 128 + (c1 >> 2)) * Kd + (c1 & 3) * 8;
  const __bf16* gB0 = W + (size_t)(bn * 128 + (c0 >> 2)) * Kd + (c0 & 3) * 8;
  const __bf16* gB1 = W + (size_t)(bn * 128 + (c1 >> 2)) * Kd + (c1 & 3) * 8;

  for (int k0 = 0; k0 < Kd; k0 += 32) {
    gload_lds16(gA0 + k0, As + c0 * 8);
    gload_lds16(gB0 + k0, Bs + c0 * 8);
    gload_lds16(gA1 + k0, As + c1 * 8);
    gload_lds16(gB1 + k0, Bs + c1 * 8);
    __syncthreads();
    bf16x8 a[4], b[4];
#pragma unroll
    for (int m = 0; m < 4; ++m)
      a[m] = *(const bf16x8*)(As + (wr * 64 + m * 16 + fr) * 32 + fq * 8);
#pragma unroll
    for (int n = 0; n < 4; ++n)
      b[n] = *(const bf16x8*)(Bs + (wc * 64 + n * 16 + fr) * 32 + fq * 8);
#pragma unroll
    for (int m = 0; m < 4; ++m)
#pragma unroll
      for (int n = 0; n < 4; ++n)
        acc[m][n] = __builtin_amdgcn_mfma_f32_16x16x32_bf16(a[m], b[n], acc[m][n], 0, 0, 0);
    __syncthreads();
  }
}

// ---------- QKV projections ----------
// z=0: Q (row-major, *qscale). z=1: K packed fragment-order. z=2: V packed
// fragment-order (computed as VT = Wv * x^T).
// PK layout: [b][h][t32=64][kc=4][lane=64][j=8]   (256KB per (b,h))
// PV layout: [b][h][t64=32][db=2][kc=4][lane=64][j=8]
__global__ __launch_bounds__(256)
void gemm_qkv(const __bf16* __restrict__ xb,
              const __bf16* __restrict__ Wq, const __bf16* __restrict__ Wk,
              const __bf16* __restrict__ Wv,
              __bf16* __restrict__ Qo, __bf16* __restrict__ Ko, __bf16* __restrict__ VTo,
              float qscale)
{
  const int z = blockIdx.z;
  const __bf16* A; const __bf16* W; __bf16* Ob; int bm, bn;
  if (z == 2)      { A = Wv; W = xb; Ob = VTo; bm = blockIdx.y; bn = blockIdx.x; }
  else if (z == 1) { A = xb; W = Wk; Ob = Ko;  bm = blockIdx.x; bn = blockIdx.y; }
  else             { A = xb; W = Wq; Ob = Qo;  bm = blockIdx.x; bn = blockIdx.y; }

  f32x4 acc[4][4] = {};
  gemm_tile_128(A, W, bm, bn, DMODEL, acc);

  const int lane = threadIdx.x & 63, wave = threadIdx.x >> 6;
  const int wr = wave >> 1, wc = wave & 1;
  const int fr = lane & 15, fq = lane >> 4;

  if (z == 0) {
#pragma unroll
    for (int m = 0; m < 4; ++m)
#pragma unroll
      for (int n = 0; n < 4; ++n) {
        const int col = bn * 128 + wc * 64 + n * 16 + fr;
#pragma unroll
        for (int j = 0; j < 4; ++j) {
          const int row = bm * 128 + wr * 64 + m * 16 + fq * 4 + j;
          Ob[(size_t)row * DMODEL + col] = (__bf16)(acc[m][n][j] * qscale);
        }
      }
  } else if (z == 1) {
    // K packed: row = token, col = feature
#pragma unroll
    for (int m = 0; m < 4; ++m)
#pragma unroll
      for (int n = 0; n < 4; ++n) {
        const int f = bn * 128 + wc * 64 + n * 16 + fr;
        const int h = f >> 6;
        const int kc = (f >> 4) & 3, hi = (f >> 3) & 1, jj = f & 7;
#pragma unroll
        for (int j = 0; j < 4; ++j) {
          const int tkn = bm * 128 + wr * 64 + m * 16 + fq * 4 + j;
          const int bb = tkn >> 11, n2 = tkn & 2047;
          const int t32 = n2 >> 5, ln2 = n2 & 31;
          const size_t idx = (((((size_t)bb * 16 + h) * 64 + t32) * 4 + kc) * 64
                              + (ln2 + (hi << 5))) * 8 + jj;
          Ob[idx] = (__bf16)acc[m][n][j];
        }
      }
  } else {
    // V packed: row = feature, col = token
#pragma unroll
    for (int m = 0; m < 4; ++m)
#pragma unroll
      for (int n = 0; n < 4; ++n) {
        const int tkn = bn * 128 + wc * 64 + n * 16 + fr;
        const int bb = tkn >> 11, n2 = tkn & 2047;
        const int t64 = n2 >> 6, w2 = n2 & 63;
        const int kc = w2 >> 4, hi = (w2 >> 3) & 1, jj = w2 & 7;
#pragma unroll
        for (int j = 0; j < 4; ++j) {
          const int f = bm * 128 + wr * 64 + m * 16 + fq * 4 + j;
          const int h = f >> 6, d = f & 63;
          const int db = d >> 5, ln2 = d & 31;
          const size_t idx = ((((((size_t)bb * 16 + h) * 32 + t64) * 2 + db) * 4 + kc) * 64
                              + (ln2 + (hi << 5))) * 8 + jj;
          Ob[idx] = (__bf16)acc[m][n][j];
        }
      }
  }
}

// ---------- output projection: in-block split-K (8 waves, 2 K-halves) ----------
// Waves 0-3: K in [0,512); waves 4-7: [512,1024). Each group keeps the r7
// 2x2 wave grid (64x64 per wave) -> same MFMA:ds_read ratio; per-wave K-loop
// halves and 2 waves/SIMD cover each other's barrier drains (was 1/SIMD).
// Group-1 partials combine through a 64KB LDS buffer; 96KB total, 1 block/CU.
// (r12-measured: ~11us faster than the 4-wave full-K version.)
__global__ __launch_bounds__(512)
void gemm_out(const __bf16* __restrict__ A, const __bf16* __restrict__ W,
              float* __restrict__ OF, const float* __restrict__ bias)
{
  __shared__ __align__(16) __bf16 As[2][128 * 32];
  __shared__ __align__(16) __bf16 Bs[2][128 * 32];
  __shared__ __align__(16) float  Cred[4 * 16 * 64 * 4];   // 64KB

  const int tid  = threadIdx.x;          // 0..511
  const int wave = tid >> 6, lane = tid & 63;
  const int g    = wave >> 2;            // K-half
  const int w4   = wave & 3;
  const int wr = w4 >> 1, wc = w4 & 1;
  const int fr = lane & 15, fq = lane >> 4;
  const int bm = blockIdx.x, bn = blockIdx.y;

  const int tid2 = tid & 255;
  const int c0 = tid2, c1 = tid2 + 256;
  const int kgo = g * 512;
  const __bf16* gA0 = A + (size_t)(bm * 128 + (c0 >> 2)) * DMODEL + (c0 & 3) * 8 + kgo;
  const __bf16* gA1 = A + (size_t)(bm * 128 + (c1 >> 2)) * DMODEL + (c1 & 3) * 8 + kgo;
  const __bf16* gB0 = W + (size_t)(bn * 128 + (c0 >> 2)) * DMODEL + (c0 & 3) * 8 + kgo;
  const __bf16* gB1 = W + (size_t)(bn * 128 + (c1 >> 2)) * DMODEL + (c1 & 3) * 8 + kgo;
  __bf16* Asg = As[g];
  __bf16* Bsg = Bs[g];

  f32x4 acc[4][4] = {};

  for (int k0 = 0; k0 < 512; k0 += 32) {
    gload_lds16(gA0 + k0, Asg + c0 * 8);
    gload_lds16(gB0 + k0, Bsg + c0 * 8);
    gload_lds16(gA1 + k0, Asg + c1 * 8);
    gload_lds16(gB1 + k0, Bsg + c1 * 8);
    __syncthreads();
    bf16x8 a[4], b[4];
#pragma unroll
    for (int m = 0; m < 4; ++m)
      a[m] = *(const bf16x8*)(Asg + (wr * 64 + m * 16 + fr) * 32 + fq * 8);
#pragma unroll
    for (int n = 0; n < 4; ++n)
      b[n] = *(const bf16x8*)(Bsg + (wc * 64 + n * 16 + fr) * 32 + fq * 8);
#pragma unroll
    for (int m = 0; m < 4; ++m)
#pragma unroll
      for (int n = 0; n < 4; ++n)
        acc[m][n] = __builtin_amdgcn_mfma_f32_16x16x32_bf16(a[m], b[n], acc[m][n], 0, 0, 0);
    __syncthreads();
  }

  // group 1 exports partials (quadrant w4): coalesced f32x4 per (m,n)
  if (g == 1) {
#pragma unroll
    for (int m = 0; m < 4; ++m)
#pragma unroll
      for (int n = 0; n < 4; ++n)
        *(f32x4*)&Cred[(((w4 * 16) + m * 4 + n) * 64 + lane) * 4] = acc[m][n];
  }
  __syncthreads();

  // group 0 combines + bias + writes out
  if (g == 0) {
#pragma unroll
    for (int m = 0; m < 4; ++m)
#pragma unroll
      for (int n = 0; n < 4; ++n) {
        const f32x4 part = *(const f32x4*)&Cred[(((w4 * 16) + m * 4 + n) * 64 + lane) * 4];
        const int col = bn * 128 + wc * 64 + n * 16 + fr;
        const float bv = bias[col];
#pragma unroll
        for (int j = 0; j < 4; ++j) {
          const int row = bm * 128 + wr * 64 + m * 16 + fq * 4 + j;
          OF[(size_t)row * DMODEL + col] = acc[m][n][j] + part[j] + bv;
        }
      }
  }
}

// ---------- flash attention (r11, verbatim — proven) ----------
// 1 wave = ONE q-tile stream; the WG's 2 waves split kv tiles by parity.
// qt descending (LPT) + bh%8 == blockIdx%8 (XCD L2). Packed K/V loads.
// Fixed-offset softmax (P=exp2(S-8), offset cancels in normalization) ->
// parity partials combine additively via LDS + 1 barrier.
// Swapped QK^T via 32x32x16 MFMA: S^T[kv][q], q = lane&31.
// C/D layout (m74/m101): col=lane&31, row=(r&3)+8*(r>>2)+4*(lane>>5).

__device__ __forceinline__ void mask_tile(f32x16& sv0, f32x16& sv1,
                                          int kv0, int q0, int ln, int hi)
{
  const int qg = q0 + ln;
#pragma unroll
  for (int r = 0; r < 16; ++r) {
    const int kvo = kv0 + (r & 3) + 8 * (r >> 2) + 4 * hi;
    if (kvo > qg)      sv0[r] = -1e30f;
    if (kvo + 32 > qg) sv1[r] = -1e30f;
  }
}

// pack exp'd P (both 32-kv halves) into PV B-fragments (half-exchange via shfl)
__device__ __forceinline__ void pack_pf(const f32x16& sv0, const f32x16& sv1,
                                        bf16x8 (&pf)[4], int hi)
{
#pragma unroll
  for (int half = 0; half < 2; ++half) {
    const int r0 = half * 8;
    {
      unsigned pk01 = pkbf(sv0[r0 + 0], sv0[r0 + 1]);
      unsigned pk23 = pkbf(sv0[r0 + 2], sv0[r0 + 3]);
      unsigned pk45 = pkbf(sv0[r0 + 4], sv0[r0 + 5]);
      unsigned pk67 = pkbf(sv0[r0 + 6], sv0[r0 + 7]);
      unsigned x01 = (unsigned)__shfl_xor((int)pk01, 32, 64);
      unsigned x23 = (unsigned)__shfl_xor((int)pk23, 32, 64);
      unsigned x45 = (unsigned)__shfl_xor((int)pk45, 32, 64);
      unsigned x67 = (unsigned)__shfl_xor((int)pk67, 32, 64);
      u32x4 uw = { hi ? x45 : pk01, hi ? x67 : pk23,
                   hi ? pk45 : x01, hi ? pk67 : x23 };
      pf[half] = __builtin_bit_cast(bf16x8, uw);
    }
    {
      unsigned pk01 = pkbf(sv1[r0 + 0], sv1[r0 + 1]);
      unsigned pk23 = pkbf(sv1[r0 + 2], sv1[r0 + 3]);
      unsigned pk45 = pkbf(sv1[r0 + 4], sv1[r0 + 5]);
      unsigned pk67 = pkbf(sv1[r0 + 6], sv1[r0 + 7]);
      unsigned x01 = (unsigned)__shfl_xor((int)pk01, 32, 64);
      unsigned x23 = (unsigned)__shfl_xor((int)pk23, 32, 64);
      unsigned x45 = (unsigned)__shfl_xor((int)pk45, 32, 64);
      unsigned x67 = (unsigned)__shfl_xor((int)pk67, 32, 64);
      u32x4 uw = { hi ? x45 : pk01, hi ? x67 : pk23,
                   hi ? pk45 : x01, hi ? pk67 : x23 };
      pf[2 + half] = __builtin_bit_cast(bf16x8, uw);
    }
  }
}

__global__ __launch_bounds__(128, 3)
void attn_kernel(const __bf16* __restrict__ Qg, const __bf16* __restrict__ PK,
                 const __bf16* __restrict__ PV, __bf16* __restrict__ Og)
{
  __shared__ __align__(16) float Cs[2][32][68];   // [parity][q][d+pad]
  __shared__ float Ls[2][2][32];                  // [parity][hi][q]

  const int tid  = threadIdx.x;
  const int p    = tid >> 6;          // wave id = kv parity
  const int lane = tid & 63;
  const int ln = lane & 31, hi = lane >> 5;
  const int bI = blockIdx.x;          // 0..2047
  const int bh = bI & 31;             // bh%8 == blockIdx%8 -> XCD L2 locality
  const int qt = 63 - (bI >> 5);      // q-tile, longest-first (LPT)
  const int b = bh >> 4, h = bh & 15;

  const int q0 = qt * 32;
  const int nt = (qt >> 1) + 1;       // kv tiles of 64

  // packed per-(b,h) bases: 131072 elems each
  const __bf16* Kp = PK + (size_t)(b * 16 + h) * (64 * 4 * 64 * 8);
  const __bf16* Vp = PV + (size_t)(b * 16 + h) * (32 * 2 * 4 * 64 * 8);
  const __bf16* Qp = Qg + ((size_t)b * SEQ + q0 + ln) * DMODEL + h * HDIM + hi * 8;

  // Q fragments (B-operand): q=ln, k = kc*16 + hi*8 + j  (Q pre-scaled 0.125*log2e)
  bf16x8 qf[4];
#pragma unroll
  for (int kc = 0; kc < 4; ++kc)
    qf[kc] = *(const bf16x8*)(Qp + kc * 16);

  f32x16 c0 = {}, c1 = {};
  float l = 0.f;

  for (int t = p; t < nt; t += 2) {
    const __bf16* kt = Kp + (size_t)t * 4096;
    const __bf16* vt = Vp + (size_t)t * 4096;

    bf16x8 kA[4], kB[4];
#pragma unroll
    for (int kc = 0; kc < 4; ++kc) {
      kA[kc] = *(const bf16x8*)(kt + (kc * 64 + lane) * 8);
      kB[kc] = *(const bf16x8*)(kt + 2048 + (kc * 64 + lane) * 8);
    }

    f32x16 s0 = {}, s1 = {};
    __builtin_amdgcn_s_setprio(1);
#pragma unroll
    for (int kc = 0; kc < 4; ++kc) {
      s0 = __builtin_amdgcn_mfma_f32_32x32x16_bf16(kA[kc], qf[kc], s0, 0, 0, 0);
      s1 = __builtin_amdgcn_mfma_f32_32x32x16_bf16(kB[kc], qf[kc], s1, 0, 0, 0);
    }
    __builtin_amdgcn_s_setprio(0);

    bf16x8 vt0[4], vt1[4];
#pragma unroll
    for (int kc = 0; kc < 4; ++kc) {
      vt0[kc] = *(const bf16x8*)(vt + (kc * 64 + lane) * 8);
      vt1[kc] = *(const bf16x8*)(vt + 2048 + (kc * 64 + lane) * 8);
    }

    if (t == nt - 1) mask_tile(s0, s1, t * 64, q0, ln, hi);

#pragma unroll
    for (int r = 0; r < 16; ++r) {
      s0[r] = __builtin_amdgcn_exp2f(s0[r] - MOFF);
      s1[r] = __builtin_amdgcn_exp2f(s1[r] - MOFF);
    }
    float s8[8];
#pragma unroll
    for (int r = 0; r < 8; ++r)
      s8[r] = (s0[r] + s0[r + 8]) + (s1[r] + s1[r + 8]);
#pragma unroll
    for (int r = 0; r < 4; ++r) s8[r] += s8[r + 4];
    l += (s8[0] + s8[1]) + (s8[2] + s8[3]);

    bf16x8 pf[4];
    pack_pf(s0, s1, pf, hi);

    __builtin_amdgcn_s_setprio(1);
#pragma unroll
    for (int kc = 0; kc < 4; ++kc)
      c0 = __builtin_amdgcn_mfma_f32_32x32x16_bf16(vt0[kc], pf[kc], c0, 0, 0, 0);
#pragma unroll
    for (int kc = 0; kc < 4; ++kc)
      c1 = __builtin_amdgcn_mfma_f32_32x32x16_bf16(vt1[kc], pf[kc], c1, 0, 0, 0);
    __builtin_amdgcn_s_setprio(0);
  }

  // ---- export both parity partials (offset-softmax partials add exactly) ----
#pragma unroll
  for (int g = 0; g < 4; ++g) {
    f32x4 v0 = { c0[4*g+0], c0[4*g+1], c0[4*g+2], c0[4*g+3] };
    f32x4 v1 = { c1[4*g+0], c1[4*g+1], c1[4*g+2], c1[4*g+3] };
    *(f32x4*)&Cs[p][ln][g * 8 + hi * 4]      = v0;   // d = g*8+hi*4+j
    *(f32x4*)&Cs[p][ln][32 + g * 8 + hi * 4] = v1;   // d = 32+...
  }
  Ls[p][hi][ln] = l;
  __syncthreads();

  // ---- each wave reduces 16 q-rows and writes out ----
  const int qe = p * 16 + (lane >> 2);
  const int de = (lane & 3) * 16;
  const float lt = Ls[0][0][qe] + Ls[0][1][qe] + Ls[1][0][qe] + Ls[1][1][qe];
  const float inv = 1.0f / lt;
  f32x4 a0 = *(const f32x4*)&Cs[0][qe][de]      + *(const f32x4*)&Cs[1][qe][de];
  f32x4 a1 = *(const f32x4*)&Cs[0][qe][de + 4]  + *(const f32x4*)&Cs[1][qe][de + 4];
  f32x4 a2 = *(const f32x4*)&Cs[0][qe][de + 8]  + *(const f32x4*)&Cs[1][qe][de + 8];
  f32x4 a3 = *(const f32x4*)&Cs[0][qe][de + 12] + *(const f32x4*)&Cs[1][qe][de + 12];
  u32x4 w0 = { pkbf(a0[0] * inv, a0[1] * inv), pkbf(a0[2] * inv, a0[3] * inv),
               pkbf(a1[0] * inv, a1[1] * inv), pkbf(a1[2] * inv, a1[3] * inv) };
  u32x4 w1 = { pkbf(a2[0] * inv, a2[1] * inv), pkbf(a2[2] * inv, a2[3] * inv),
               pkbf(a3[0] * inv, a3[1] * inv), pkbf(a3[2] * inv, a3[3] * inv) };
  __bf16* Op = Og + ((size_t)b * SEQ + q0 + qe) * DMODEL + h * HDIM + de;
  *(u32x4*)(Op)     = w0;
  *(u32x4*)(Op + 8) = w1;
}

// ---------- launch ----------
extern "C" void kernel_launch(void* const* d_in, const int* in_sizes, int n_in,
                              void* d_out, int out_size, void* d_ws, size_t ws_size,
                              hipStream_t stream) {
  (void)in_sizes; (void)n_in; (void)out_size; (void)ws_size;
  const float* x  = (const float*)d_in[0];
  const float* Wq = (const float*)d_in[1];
  const float* Wk = (const float*)d_in[2];
  const float* Wv = (const float*)d_in[3];
  const float* Wo = (const float*)d_in[4];
  const float* bo = (const float*)d_in[5];
  float* out = (float*)d_out;

  __bf16* ws  = (__bf16*)d_ws;
  __bf16* xb  = ws;                                   // 4M elems
  __bf16* Wqb = xb  + (size_t)MTOT * DMODEL;
  __bf16* Wkb = Wqb + (size_t)DMODEL * DMODEL;
  __bf16* Wvb = Wkb + (size_t)DMODEL * DMODEL;
  __bf16* Wob = Wvb + (size_t)DMODEL * DMODEL;
  __bf16* Qb  = Wob + (size_t)DMODEL * DMODEL;        // 4M
  __bf16* Kpk = Qb  + (size_t)MTOT * DMODEL;          // 4M, packed fragment order
  __bf16* Vpk = Kpk + (size_t)MTOT * DMODEL;          // 4M, packed fragment order
  __bf16* ctxb = xb;  // reuse: x is dead after QKV projections

  cast_all<<<dim3(256, 5), 256, 0, stream>>>(x, Wq, Wk, Wv, Wo,
                                             xb, Wqb, Wkb, Wvb, Wob);

  // scale = 1/sqrt(64) * log2(e), folded into Q so softmax uses exp2
  const float qscale = 0.125f * 1.4426950408889634f;
  gemm_qkv<<<dim3(32, 8, 3), 256, 0, stream>>>(xb, Wqb, Wkb, Wvb, Qb, Kpk, Vpk, qscale);

  attn_kernel<<<dim3(2048), 128, 0, stream>>>(Qb, Kpk, Vpk, ctxb);

  gemm_out<<<dim3(32, 8), 512, 0, stream>>>(ctxb, Wob, out, bo);
}